// Round 1
// baseline (87.473 us; speedup 1.0000x reference)
//
#include <hip/hip_runtime.h>
#include <hip/hip_bf16.h>
#include <math.h>

// S4D kernel: out[h,l] = 2*Re( sum_n Cc'[h,n] * exp(dtA[h,n]*l) ), l in [0,4096)
// H=1024, N2=32, L=4096.  Strategy: per-block h, per-thread l-stride-256
// geometric recurrence S <- S*R with R = exp(dtA*256), setup in fp64.

constexpr int H_  = 1024;
constexpr int N2_ = 32;
constexpr int L_  = 4096;
constexpr int BT_ = 256;          // threads per block
constexpr int NJ_ = L_ / BT_;     // 16 l-values per thread

__global__ __launch_bounds__(BT_) void s4d_kernel(
    const float* __restrict__ log_dt,
    const float* __restrict__ C,
    const float* __restrict__ log_A_real,
    const float* __restrict__ A_imag,
    float* __restrict__ out)
{
    __shared__ float  sCre[N2_], sCim[N2_];   // Cc' = Cc*(e^{dtA}-1)/A
    __shared__ float  sAl2[N2_];              // dtA_re * log2(e)  (exp2 slope per step)
    __shared__ float  sRre[N2_], sRim[N2_];   // R = exp(dtA * BT_)
    __shared__ double sRho[N2_];              // phase in revolutions per step = dtA_im/(2*pi)

    const int h = blockIdx.x;
    const int t = threadIdx.x;

    if (t < N2_) {
        const int n = t;
        const double dt  = exp((double)log_dt[h]);
        const double ar  = -exp((double)log_A_real[h * N2_ + n]);
        const double ai  = (double)A_imag[h * N2_ + n];
        const double dtar = ar * dt;
        const double dtai = ai * dt;

        // e^{dtA} - 1
        const double em  = exp(dtar);
        const double ere = em * cos(dtai) - 1.0;
        const double eim = em * sin(dtai);

        // Cc * (e^{dtA}-1) / A   (divide = multiply by conj(A)/|A|^2)
        const double cre = (double)C[(h * N2_ + n) * 2 + 0];
        const double cim = (double)C[(h * N2_ + n) * 2 + 1];
        const double inv = 1.0 / (ar * ar + ai * ai);
        const double qre = (ere * ar + eim * ai) * inv;
        const double qim = (eim * ar - ere * ai) * inv;
        sCre[n] = (float)(cre * qre - cim * qim);
        sCim[n] = (float)(cre * qim + cim * qre);

        sAl2[n] = (float)(dtar * 1.4426950408889634);   // log2(e)
        const double rho = dtai * 0.15915494309189535;  // 1/(2*pi), revolutions/step
        sRho[n] = rho;

        // stride ratio R = exp(dtA * BT_), phase reduced mod 1 rev in fp64
        const double rmag = exp(dtar * (double)BT_);
        double rrev = rho * (double)BT_;
        rrev -= floor(rrev);
        sRre[n] = (float)(rmag * cos(rrev * 6.283185307179586));
        sRim[n] = (float)(rmag * sin(rrev * 6.283185307179586));
    }
    __syncthreads();

    float Sre[N2_], Sim[N2_], Rre[N2_], Rim[N2_];
    float acc = 0.f;

    // init: S_n = Cc'_n * exp(dtA_n * t), direct eval with fp64 phase reduction
    #pragma unroll
    for (int n = 0; n < N2_; n++) {
        const float mag = exp2f(sAl2[n] * (float)t);
        const double rev = sRho[n] * (double)t;
        const float fr = (float)(rev - floor(rev));
        const float s = __builtin_amdgcn_sinf(fr);   // v_sin_f32: input in revolutions
        const float c = __builtin_amdgcn_cosf(fr);
        const float cr = sCre[n], ci = sCim[n];
        Sre[n] = mag * (cr * c - ci * s);
        Sim[n] = mag * (cr * s + ci * c);
        Rre[n] = sRre[n];
        Rim[n] = sRim[n];
        acc += Sre[n];
    }

    float* op = out + (size_t)h * L_ + t;
    op[0] = 2.f * acc;

    // recurrence: S <- S * R advances l by 256
    #pragma unroll 1
    for (int j = 1; j < NJ_; j++) {
        acc = 0.f;
        #pragma unroll
        for (int n = 0; n < N2_; n++) {
            const float nre = Sre[n] * Rre[n] - Sim[n] * Rim[n];
            const float nim = Sre[n] * Rim[n] + Sim[n] * Rre[n];
            Sre[n] = nre;
            Sim[n] = nim;
            acc += nre;
        }
        op[j * BT_] = 2.f * acc;
    }
}

extern "C" void kernel_launch(void* const* d_in, const int* in_sizes, int n_in,
                              void* d_out, int out_size, void* d_ws, size_t ws_size,
                              hipStream_t stream) {
    // inputs: [0]=L (int scalar, known 4096), [1]=log_dt (H,), [2]=C (H,N2,2),
    //         [3]=log_A_real (H,N2), [4]=A_imag (H,N2); output: (H, L) fp32
    const float* log_dt     = (const float*)d_in[1];
    const float* C          = (const float*)d_in[2];
    const float* log_A_real = (const float*)d_in[3];
    const float* A_imag     = (const float*)d_in[4];
    float* out = (float*)d_out;

    s4d_kernel<<<dim3(H_), dim3(BT_), 0, stream>>>(log_dt, C, log_A_real, A_imag, out);
}

// Round 2
// 84.824 us; speedup vs baseline: 1.0312x; 1.0312x over previous
//
#include <hip/hip_runtime.h>
#include <hip/hip_bf16.h>
#include <math.h>

// S4D: out[h,l] = 2*Re( sum_n Cc'[h,n] * exp(dtA[h,n]*l) ), H=1024, N2=32, L=4096.
// Per-block h; thread t owns l = t + 256*j (coalesced). Geometric recurrence
// S <- S*R, R = exp(dtA*256). Main loop written as float2 ext-vectors so ISel
// emits v_pk_mul_f32 / v_pk_fma_f32 (packed fp32): 3 inst per mode-step vs 5.
// fp64 only for the two phase mod-1 reductions in the 32-thread setup.

typedef float v2f __attribute__((ext_vector_type(2)));

constexpr int H_  = 1024;
constexpr int N2_ = 32;
constexpr int L_  = 4096;
constexpr int BT_ = 256;          // threads per block
constexpr int NJ_ = L_ / BT_;     // 16 l-values per thread

__global__ __launch_bounds__(BT_) void s4d_kernel(
    const float* __restrict__ log_dt,
    const float* __restrict__ C,
    const float* __restrict__ log_A_real,
    const float* __restrict__ A_imag,
    float* __restrict__ out)
{
    __shared__ v2f   sC[N2_];     // Cc' = Cc*(e^{dtA}-1)/A
    __shared__ v2f   sRa[N2_];    // (Rre, Rre)
    __shared__ v2f   sRb[N2_];    // (-Rim, Rim)
    __shared__ float sAl2[N2_];   // dtA_re * log2(e)  (per-step exp2 slope)
    __shared__ float sRho[N2_];   // fract(dtA_im / 2pi)  (revolutions per step)

    const int h = blockIdx.x;
    const int t = threadIdx.x;

    if (t < N2_) {
        const int n = t;
        const float dt   = expf(log_dt[h]);
        const float ar   = -expf(log_A_real[h * N2_ + n]);
        const float ai   = A_imag[h * N2_ + n];
        const float dtar = ar * dt;
        const float dtai = ai * dt;

        // Cc' = Cc * (e^{dtA}-1) / A    (all fp32; no cancellation hazard here)
        const float em  = expf(dtar);
        const float ere = em * cosf(dtai) - 1.0f;
        const float eim = em * sinf(dtai);
        const float cre = C[(h * N2_ + n) * 2 + 0];
        const float cim = C[(h * N2_ + n) * 2 + 1];
        const float inv = 1.0f / (ar * ar + ai * ai);
        const float qre = (ere * ar + eim * ai) * inv;
        const float qim = (eim * ar - ere * ai) * inv;
        sC[n] = (v2f){cre * qre - cim * qim, cre * qim + cim * qre};

        sAl2[n] = dtar * 1.442695040888963f;   // log2(e)

        // phase reductions in fp64 (hardware mul+floor only, no libm)
        const double rho = (double)dtai * 0.15915494309189535;  // rev per step
        sRho[n] = (float)(rho - floor(rho));

        double prv = rho * 256.0;
        prv -= floor(prv);
        const float prf  = (float)prv;
        const float rmag = __builtin_amdgcn_exp2f(dtar * (256.0f * 1.442695040888963f));
        const float rre  = rmag * __builtin_amdgcn_cosf(prf);  // v_cos: revolutions
        const float rim  = rmag * __builtin_amdgcn_sinf(prf);
        sRa[n] = (v2f){rre, rre};
        sRb[n] = (v2f){-rim, rim};
    }
    __syncthreads();

    v2f S[N2_], Ra[N2_], Rb[N2_];
    v2f acca = (v2f){0.f, 0.f};
    v2f accb = (v2f){0.f, 0.f};
    const float tf = (float)t;

    // init: S_n = Cc'_n * exp(dtA_n * t), HW trans + fp32 phase
    #pragma unroll
    for (int n = 0; n < N2_; n++) {
        const float mag = __builtin_amdgcn_exp2f(sAl2[n] * tf);
        const float ph  = sRho[n] * tf;
        const float fr  = ph - floorf(ph);
        const float s   = __builtin_amdgcn_sinf(fr);
        const float c   = __builtin_amdgcn_cosf(fr);
        const v2f  cn   = sC[n];
        v2f Sn;
        Sn.x = mag * (cn.x * c - cn.y * s);
        Sn.y = mag * (cn.x * s + cn.y * c);
        S[n]  = Sn;
        Ra[n] = sRa[n];
        Rb[n] = sRb[n];
        if (n & 1) accb += Sn; else acca += Sn;
    }

    float* op = out + (size_t)h * L_ + t;
    op[0] = 2.f * (acca.x + accb.x);

    // recurrence: S <- S*R advances l by 256.  Per mode: pk_mul + pk_fma + pk_add.
    #pragma unroll 1
    for (int j = 1; j < NJ_; j++) {
        acca = (v2f){0.f, 0.f};
        accb = (v2f){0.f, 0.f};
        #pragma unroll
        for (int n = 0; n < N2_; n++) {
            const v2f Sn  = S[n];
            const v2f Ssw = Sn.yx;                         // folds into op_sel
            const v2f Sn2 = __builtin_elementwise_fma(Ssw, Rb[n], Sn * Ra[n]);
            S[n] = Sn2;
            if (n & 1) accb += Sn2; else acca += Sn2;
        }
        op[j * BT_] = 2.f * (acca.x + accb.x);
    }
}

extern "C" void kernel_launch(void* const* d_in, const int* in_sizes, int n_in,
                              void* d_out, int out_size, void* d_ws, size_t ws_size,
                              hipStream_t stream) {
    const float* log_dt     = (const float*)d_in[1];
    const float* C          = (const float*)d_in[2];
    const float* log_A_real = (const float*)d_in[3];
    const float* A_imag     = (const float*)d_in[4];
    float* out = (float*)d_out;

    s4d_kernel<<<dim3(H_), dim3(BT_), 0, stream>>>(log_dt, C, log_A_real, A_imag, out);
}